// Round 14
// baseline (95.169 us; speedup 1.0000x reference)
//
#include <hip/hip_runtime.h>

#define BB 512
#define TT 512
#define KK 128
#define CS 136   // chain stride in shorts: 68 dwords = +4 banks per chain

typedef __attribute__((ext_vector_type(8))) short short8;   // 8 x bf16 bits
typedef __attribute__((ext_vector_type(4))) float f32x4;

// f32 -> bf16 bits, round-to-nearest-even (finite values)
__device__ __forceinline__ unsigned short f2bf(float f) {
  unsigned u = __float_as_uint(f);
  unsigned r = ((u >> 16) & 1u) + 0x7fffu;
  return (unsigned short)((u + r) >> 16);
}
__device__ __forceinline__ float bf2f(unsigned short h) {
  return __uint_as_float(((unsigned)h) << 16);
}
__device__ __forceinline__ int fexpo(float f) {
  return (int)((__float_as_uint(f) >> 23) & 0xFF) - 127;
}
// Drain LDS ops only; global prefetch loads stay in flight across the barrier.
__device__ __forceinline__ void lds_barrier() {
  asm volatile("s_waitcnt lgkmcnt(0)\n\ts_barrier" ::: "memory");
}

// K1: one block per (batch-quad, direction). 512 threads = 8 waves.
// FOUR chains (batches 4q..4q+3) packed into MFMA A-rows: A[row][k] =
// state[row&3][k] (A layout: row = lane&15 -> row&3 = lc&3). Wave wv owns
// col-tile wv: 4 MFMAs/step serve 4 chains = 8 MFMAs per chain-step.
// D layout: row = 4*(lane>>4)+reg -> chain = reg. Lane (wv,lg,lc) finalizes
// chain lg, col 16wv+lc: one epilogue value / pot load / ds_write_b16 per
// lane. 8 waves x 64 lanes = 4 chains x 128 cols.
// State: scaled bf16 in LDS, chain stride CS=136 shorts so the 4 chain
// addresses in each 16-lane quarter hit banks {0,4,8,12}+c (conflict-free).
// Per-chain lagged power-of-2 rescale: stored_new = matvec * 2^(pot*C - d_c),
// d_c = exponent of stored_c[0]; M_c += d_c; true value = stored * 2^M_c.
// dir=0 fwd: w_t = u_t.(E^T w_{t-1}), t=1..256; dir=1 bwd: y_{t-1} =
// u_{t-1}.(E y_t), t=510..257, then y = E y_257 (no u). K2 combines.
__global__ __launch_bounds__(512, 1) void crf_half_kernel(
    const float* __restrict__ pot, const int* __restrict__ tags,
    const float* __restrict__ trans, unsigned short* __restrict__ wsv,
    float* __restrict__ wsm) {
  const float C = 1.4426950408889634f;    // 1/ln2
  const int bid = blockIdx.x;
  const int quad = bid >> 1, dir = bid & 1;
  const int tid = threadIdx.x;            // 0..511
  const int lane = tid & 63;
  const int wv = tid >> 6;                // col-tile 0..7
  const int lg = lane >> 4;               // epilogue chain / A k-subgroup
  const int lc = lane & 15;               // col within tile
  const int crA = lc & 3;                 // A-row chain

  __shared__ alignas(16) unsigned short sbuf[2][4][CS];  // [parity][chain][j]
  __shared__ int dbuf[2][4];
  __shared__ float red[8];

  // ---- sequence scores (fwd blocks; bwd writes zeros) ----
  float sc = 0.f;
  if (dir == 0) {
    int bb = 4 * quad + (tid >> 7);       // 128 threads per batch
    int base = 4 * (tid & 127);           // 4 time-steps per thread
    const float* pbs = pot + (size_t)bb * TT * KK;
    int4 tg = *(const int4*)&tags[bb * TT + base];
    sc = pbs[(size_t)(base + 0) * KK + tg.x] + pbs[(size_t)(base + 1) * KK + tg.y]
       + pbs[(size_t)(base + 2) * KK + tg.z] + pbs[(size_t)(base + 3) * KK + tg.w];
    sc += trans[tg.x * KK + tg.y] + trans[tg.y * KK + tg.z] +
          trans[tg.z * KK + tg.w];
    if (base + 4 < TT) sc += trans[tg.w * KK + tags[bb * TT + base + 4]];
  }
  #pragma unroll
  for (int off = 32; off; off >>= 1) sc += __shfl_xor(sc, off, 64);
  if (lane == 0) red[wv] = sc;            // batch c partials in red[2c],red[2c+1]

  // ---- B fragments: this wave's col-tile, 4 k-chunks (bwd: E^T) ----
  short8 Bf[4];
  {
    const int j = 16 * wv + lc;
    #pragma unroll
    for (int kc = 0; kc < 4; ++kc) {
      #pragma unroll
      for (int e = 0; e < 8; ++e) {
        int k = 32 * kc + 8 * lg + e;
        float tv = (dir == 0) ? trans[k * KK + j] : trans[j * KK + k];
        Bf[kc][e] = (short)f2bf(__builtin_amdgcn_exp2f(tv * C));
      }
    }
  }

  // ---- init: state[0][c] = u_{t0} of batch 4q+c ----
  {
    int c = tid >> 7, j = tid & 127;
    int bb = 4 * quad + c;
    int ri = dir ? (TT - 1) : 0;
    float w0 = __builtin_amdgcn_exp2f(
        pot[(size_t)bb * TT * KK + (size_t)ri * KK + j] * C);
    sbuf[0][c][j] = f2bf(w0);
    if (j == 0) dbuf[0][c] = fexpo(w0);
  }
  __syncthreads();

  const int nst = dir ? 255 : 256;
  const int r0 = dir ? (TT - 2) : 1;
  const int st = dir ? -1 : 1;
  const int jW = 16 * wv + lc;            // this lane's output column
  const float* pp = pot + (size_t)(4 * quad + lg) * TT * KK + jW;
  int Mi = 0;
  const f32x4 z4 = {0.f, 0.f, 0.f, 0.f};

  // 4-phase pot pipeline, one float per phase
  float p0 = pp[(size_t)(r0 + 0 * st) * KK];
  float p1 = pp[(size_t)(r0 + 1 * st) * KK];
  float p2 = pp[(size_t)(r0 + 2 * st) * KK];
  float p3 = pp[(size_t)(r0 + 3 * st) * KK];

  auto step = [&](int it, float& q) {
    const int p = it & 1, wr = p ^ 1;
    const unsigned short* sp = &sbuf[p][crA][8 * lg];
    short8 A0 = *(const short8*)(sp);        // k =      8lg+e
    short8 A1 = *(const short8*)(sp + 32);   // k = 32 + 8lg+e
    short8 A2 = *(const short8*)(sp + 64);
    short8 A3 = *(const short8*)(sp + 96);
    int d = dbuf[p][lg];
    float cp = q;                            // pot loaded 4 steps ago
    int rn = r0 + st * (it + 4);             // fwd <=260, bwd >=252: in range
    q = pp[(size_t)rn * KK];
    f32x4 a  = __builtin_amdgcn_mfma_f32_16x16x32_bf16(A3, Bf[3], z4, 0, 0, 0);
    f32x4 b2 = __builtin_amdgcn_mfma_f32_16x16x32_bf16(A2, Bf[2], z4, 0, 0, 0);
    a  = __builtin_amdgcn_mfma_f32_16x16x32_bf16(A1, Bf[1], a,  0, 0, 0);
    b2 = __builtin_amdgcn_mfma_f32_16x16x32_bf16(A0, Bf[0], b2, 0, 0, 0);
    // D reg r = chain r; this lane takes chain lg
    float za = (lg == 0) ? a[0]  : ((lg == 1) ? a[1]  : ((lg == 2) ? a[2]  : a[3]));
    float zb = (lg == 0) ? b2[0] : ((lg == 1) ? b2[1] : ((lg == 2) ? b2[2] : b2[3]));
    float z = za + zb;
    const bool lastB = (dir == 1) && (it == nst - 1);  // y = E z (no u)
    float pe = lastB ? 0.f : cp;
    float v = z * __builtin_amdgcn_exp2f(fmaf(pe, C, (float)(-d)));
    Mi += d;
    sbuf[wr][lg][jW] = f2bf(v);
    if (wv == 0 && lc == 0) dbuf[wr][lg] = fexpo(v);   // lanes 0,16,32,48
    lds_barrier();   // lgkmcnt(0)+s_barrier; global loads stay in flight
  };

  const int nq = nst >> 2;                   // fwd 64, bwd 63
  for (int itq = 0; itq < nq; ++itq) {
    int it = itq << 2;
    step(it + 0, p0);
    step(it + 1, p1);
    step(it + 2, p2);
    step(it + 3, p3);
  }
  if (dir == 1) {                            // bwd tail: steps 252..254
    step(252, p0);
    step(253, p1);
    step(254, p2);
  }

  // ---- export final state + M + scores ----
  const int fin = nst & 1;                   // fwd parity 0, bwd parity 1
  {
    int c = tid >> 7, j = tid & 127;
    wsv[((size_t)bid * 4 + c) * KK + j] = sbuf[fin][c][j];
  }
  if (wv == 0 && lc == 0) wsm[bid * 8 + lg] = (float)Mi;
  if (tid < 4) wsm[bid * 8 + 4 + tid] = red[2 * tid] + red[2 * tid + 1];
}

// K2: combine. One wave per batch: Z*2^(Mf+Mb) = wF . yB.
__global__ __launch_bounds__(256) void crf_combine_kernel(
    const unsigned short* __restrict__ wsv, const float* __restrict__ wsm,
    float* __restrict__ out) {
  const float LN2 = 0.6931471805599453f;
  const int tid = threadIdx.x;
  const int lane = tid & 63, wid = tid >> 6;
  const int b = blockIdx.x * 4 + wid;
  const int quad = b >> 2, c = b & 3;
  const unsigned short* wf = wsv + ((size_t)(quad * 2 + 0) * 4 + c) * KK;
  const unsigned short* yb = wsv + ((size_t)(quad * 2 + 1) * 4 + c) * KK;
  float pr = bf2f(wf[lane]) * bf2f(yb[lane]) +
             bf2f(wf[lane + 64]) * bf2f(yb[lane + 64]);
  #pragma unroll
  for (int off = 32; off; off >>= 1) pr += __shfl_xor(pr, off, 64);
  if (lane == 0) {
    float Mf  = wsm[(quad * 2 + 0) * 8 + c];
    float Mb  = wsm[(quad * 2 + 1) * 8 + c];
    float scv = wsm[(quad * 2 + 0) * 8 + 4 + c];
    out[b] = scv - (Mf + Mb + __builtin_amdgcn_logf(pr)) * LN2;
  }
}

extern "C" void kernel_launch(void* const* d_in, const int* in_sizes, int n_in,
                              void* d_out, int out_size, void* d_ws, size_t ws_size,
                              hipStream_t stream) {
  const float* pot = (const float*)d_in[0];
  const int* tags = (const int*)d_in[1];
  const float* trans = (const float*)d_in[2];
  float* out = (float*)d_out;
  unsigned short* wsv = (unsigned short*)d_ws;            // 256 x 4 x 128 bf16
  float* wsm = (float*)((char*)d_ws + (size_t)256 * 4 * KK * 2);  // 256 x 8 f32
  crf_half_kernel<<<256, 512, 0, stream>>>(pot, tags, trans, wsv, wsm);
  crf_combine_kernel<<<BB / 4, 256, 0, stream>>>(wsv, wsm, out);
}

// Round 15
// 81.987 us; speedup vs baseline: 1.1608x; 1.1608x over previous
//
#include <hip/hip_runtime.h>

#define BB 512
#define TT 512
#define KK 128
#define CS 160   // chain stride in shorts: 320B = 80 dw == +16 banks per chain

typedef __attribute__((ext_vector_type(8))) short short8;   // 8 x bf16 bits
typedef __attribute__((ext_vector_type(4))) float f32x4;

// f32 -> bf16 bits, round-to-nearest-even (finite values)
__device__ __forceinline__ unsigned short f2bf(float f) {
  unsigned u = __float_as_uint(f);
  unsigned r = ((u >> 16) & 1u) + 0x7fffu;
  return (unsigned short)((u + r) >> 16);
}
__device__ __forceinline__ float bf2f(unsigned short h) {
  return __uint_as_float(((unsigned)h) << 16);
}
// Drain LDS ops only; global prefetch loads stay in flight across the barrier.
__device__ __forceinline__ void lds_barrier() {
  asm volatile("s_waitcnt lgkmcnt(0)\n\ts_barrier" ::: "memory");
}

// K1: one block per (batch-pair, direction). 256 threads = 4 waves.
// TWO chains (batches 2p, 2p+1) packed into MFMA A-rows by parity:
//   A[row][k] = state[row&1][k]   (A layout: row = lane&15, k = 8*(lane>>4)+e)
// Wave wv computes col-tiles {2wv, 2wv+1} for both chains: 8 MFMAs/wave/step.
// D layout (HW-verified): col = lane&15, row = 4*(lane>>4)+reg -> chain = reg&1.
// Lane (lg,lc) finalizes chain cW=lg&1, col jW=32wv+16(lg>>1)+lc.
// LDS diet vs R13:
//  - chain stride CS=160 shorts: the 8 (crA,lg) read addresses per b128 hit
//    8 DISTINCT bank quads (conflict-free); writes spread all 32 banks 2-way.
//  - NO dbuf: the scale exponent d_c = exponent of state[c][0] is extracted
//    from A0 element 0 of lanes 0/1 via v_readlane (SALU) - two fewer LDS
//    ops per wave per step.
// Scaled bf16 state, lagged power-of-2 rescale: stored_new = matvec *
// 2^(pot*C - d_c); M_c += d_c; true value = stored * 2^M_c.
// dir=0 fwd: w_t = u_t.(E^T w_{t-1}), t=1..256; dir=1 bwd: y_{t-1} =
// u_{t-1}.(E y_t), t=510..257, then y = E y_257 (no u). K2 combines.
__global__ __launch_bounds__(256, 2) void crf_half_kernel(
    const float* __restrict__ pot, const int* __restrict__ tags,
    const float* __restrict__ trans, unsigned short* __restrict__ wsv,
    float4* __restrict__ wsm) {
  const float C = 1.4426950408889634f;    // 1/ln2
  const int bid = blockIdx.x;
  const int pair = bid >> 1, dir = bid & 1;
  const int tid = threadIdx.x;            // 0..255
  const int lane = tid & 63;
  const int wv = tid >> 6;                // wave 0..3 -> col-tiles 2wv,2wv+1
  const int lg = lane >> 4;               // lane group 0..3
  const int lc = lane & 15;               // column within 16-tile

  __shared__ alignas(16) unsigned short sbuf[2][2][CS];  // [parity][chain][j]
  __shared__ float red[4];

  // ---- sequence scores for both batches (fwd blocks only; bwd writes 0) ----
  float sc = 0.f;
  if (dir == 0) {
    int bb = 2 * pair + (tid >> 7);       // threads 0-127 -> b0, 128-255 -> b1
    int base = 4 * (tid & 127);
    const float* pbs = pot + (size_t)bb * TT * KK;
    int4 tg = *(const int4*)&tags[bb * TT + base];
    sc = pbs[(size_t)(base + 0) * KK + tg.x] + pbs[(size_t)(base + 1) * KK + tg.y]
       + pbs[(size_t)(base + 2) * KK + tg.z] + pbs[(size_t)(base + 3) * KK + tg.w];
    sc += trans[tg.x * KK + tg.y] + trans[tg.y * KK + tg.z] +
          trans[tg.z * KK + tg.w];
    if (base + 4 < TT) sc += trans[tg.w * KK + tags[bb * TT + base + 4]];
  }
  #pragma unroll
  for (int off = 32; off; off >>= 1) sc += __shfl_xor(sc, off, 64);
  if (lane == 0) red[wv] = sc;            // b0 partials red[0,1]; b1 red[2,3]

  // ---- B fragments: 2 tiles x 4 k-chunks (bwd: transposed E) ----
  short8 Bf0[4], Bf1[4];
  const int jT0 = 32 * wv + lc, jT1 = jT0 + 16;
  #pragma unroll
  for (int kc = 0; kc < 4; ++kc) {
    #pragma unroll
    for (int e = 0; e < 8; ++e) {
      int k = 32 * kc + 8 * lg + e;
      float t0 = (dir == 0) ? trans[k * KK + jT0] : trans[jT0 * KK + k];
      float t1 = (dir == 0) ? trans[k * KK + jT1] : trans[jT1 * KK + k];
      Bf0[kc][e] = (short)f2bf(__builtin_amdgcn_exp2f(t0 * C));
      Bf1[kc][e] = (short)f2bf(__builtin_amdgcn_exp2f(t1 * C));
    }
  }

  // ---- init: state[0][c] = u_{t0} of batch 2p+c (fwd t0=0, bwd t0=511) ----
  {
    int c = tid >> 7, j = tid & 127;
    int bb = 2 * pair + c;
    int ri = dir ? (TT - 1) : 0;
    float w0 = __builtin_amdgcn_exp2f(pot[(size_t)bb * TT * KK +
                                          (size_t)ri * KK + j] * C);
    sbuf[0][c][j] = f2bf(w0);
  }
  __syncthreads();

  const int nst = dir ? 255 : 256;
  const int r0 = dir ? (TT - 2) : 1;
  const int st = dir ? -1 : 1;
  // per-lane epilogue identity
  const int cW = lg & 1;                        // chain this lane finalizes
  const int jW = 32 * wv + 16 * (lg >> 1) + lc; // its output column
  const float* pp = pot + (size_t)(2 * pair + cW) * TT * KK + jW;
  const int crA = lc & 1;                       // A-row chain parity (reads)
  int Mi0 = 0, Mi1 = 0;
  const f32x4 kZero = {0.f, 0.f, 0.f, 0.f};

  // 4-phase pot pipeline, one float per phase
  float p0 = pp[(size_t)(r0 + 0 * st) * KK];
  float p1 = pp[(size_t)(r0 + 1 * st) * KK];
  float p2 = pp[(size_t)(r0 + 2 * st) * KK];
  float p3 = pp[(size_t)(r0 + 3 * st) * KK];

  auto step = [&](int it, float& q) {
    const int p = it & 1, wr = p ^ 1;
    const unsigned short* sp = &sbuf[p][crA][8 * lg];
    short8 A0 = *(const short8*)(sp);        // k =      8lg+e
    short8 A1 = *(const short8*)(sp + 32);   // k = 32 + 8lg+e
    short8 A2 = *(const short8*)(sp + 64);
    short8 A3 = *(const short8*)(sp + 96);
    // scale exponents from state[c][0]: lane 0 (lg=0,crA=0) has A0[0] =
    // state[0][0]; lane 1 (crA=1) has state[1][0]. readlane -> uniform SGPR.
    int e0 = (int)(unsigned short)A0[0];
    int d0 = ((__builtin_amdgcn_readlane(e0, 0) >> 7) & 0xFF) - 127;
    int d1 = ((__builtin_amdgcn_readlane(e0, 1) >> 7) & 0xFF) - 127;
    float cp = q;                            // pot loaded 4 steps ago
    int rn = r0 + st * (it + 4);             // fwd <=260, bwd >=252: in range
    q = pp[(size_t)rn * KK];
    f32x4 a0, a1;
    __builtin_amdgcn_s_setprio(1);
    a0 = __builtin_amdgcn_mfma_f32_16x16x32_bf16(A3, Bf0[3], kZero, 0, 0, 0);
    a1 = __builtin_amdgcn_mfma_f32_16x16x32_bf16(A3, Bf1[3], kZero, 0, 0, 0);
    a0 = __builtin_amdgcn_mfma_f32_16x16x32_bf16(A2, Bf0[2], a0, 0, 0, 0);
    a1 = __builtin_amdgcn_mfma_f32_16x16x32_bf16(A2, Bf1[2], a1, 0, 0, 0);
    a0 = __builtin_amdgcn_mfma_f32_16x16x32_bf16(A1, Bf0[1], a0, 0, 0, 0);
    a1 = __builtin_amdgcn_mfma_f32_16x16x32_bf16(A1, Bf1[1], a1, 0, 0, 0);
    a0 = __builtin_amdgcn_mfma_f32_16x16x32_bf16(A0, Bf0[0], a0, 0, 0, 0);
    a1 = __builtin_amdgcn_mfma_f32_16x16x32_bf16(A0, Bf1[0], a1, 0, 0, 0);
    __builtin_amdgcn_s_setprio(0);
    // rows alternate chains (row parity = reg&1); take reg cW, tile lg>>1
    float z0 = cW ? a0[1] : a0[0];
    float z1 = cW ? a1[1] : a1[0];
    float z = (lg & 2) ? z1 : z0;
    const bool lastB = (dir == 1) && (it == nst - 1);  // y = E z (no u)
    float pe = lastB ? 0.f : cp;
    int dc = cW ? d1 : d0;
    float v = z * __builtin_amdgcn_exp2f(fmaf(pe, C, (float)(-dc)));
    Mi0 += d0; Mi1 += d1;
    sbuf[wr][cW][jW] = f2bf(v);
    lds_barrier();   // lgkmcnt(0)+s_barrier; global loads stay in flight
  };

  const int nq = nst >> 2;                   // fwd 64, bwd 63
  for (int itq = 0; itq < nq; ++itq) {
    int it = itq << 2;
    step(it + 0, p0);
    step(it + 1, p1);
    step(it + 2, p2);
    step(it + 3, p3);
  }
  if (dir == 1) {                            // bwd tail: steps 252..254
    step(252, p0);
    step(253, p1);
    step(254, p2);
  }

  // ---- export final state + M + scores ----
  const int fin = nst & 1;                   // fwd parity 0, bwd parity 1
  {
    int c = tid >> 7, j = tid & 127;
    wsv[((size_t)bid * 2 + c) * KK + j] = sbuf[fin][c][j];
  }
  if (tid == 0) {
    float4 m;
    m.x = (float)Mi0; m.y = (float)Mi1;
    m.z = red[0] + red[1]; m.w = red[2] + red[3];
    wsm[bid] = m;
  }
}

// K2: combine. One wave per batch: Z*2^(Mf+Mb) = wF . yB.
__global__ __launch_bounds__(256) void crf_combine_kernel(
    const unsigned short* __restrict__ wsv, const float4* __restrict__ wsm,
    float* __restrict__ out) {
  const float LN2 = 0.6931471805599453f;
  const int tid = threadIdx.x;
  const int lane = tid & 63, wid = tid >> 6;
  const int b = blockIdx.x * 4 + wid;
  const int pair = b >> 1, c = b & 1;
  const unsigned short* wf = wsv + ((size_t)(2 * pair + 0) * 2 + c) * KK;
  const unsigned short* yb = wsv + ((size_t)(2 * pair + 1) * 2 + c) * KK;
  float pr = bf2f(wf[lane]) * bf2f(yb[lane]) +
             bf2f(wf[lane + 64]) * bf2f(yb[lane + 64]);
  #pragma unroll
  for (int off = 32; off; off >>= 1) pr += __shfl_xor(pr, off, 64);
  if (lane == 0) {
    float4 mf = wsm[2 * pair + 0];           // fwd: {M0, M1, sc0, sc1}
    float4 mb = wsm[2 * pair + 1];           // bwd: {M0, M1, 0, 0}
    float Mf = c ? mf.y : mf.x;
    float Mb = c ? mb.y : mb.x;
    float scv = c ? mf.w : mf.z;
    out[b] = scv - (Mf + Mb + __builtin_amdgcn_logf(pr)) * LN2;
  }
}

extern "C" void kernel_launch(void* const* d_in, const int* in_sizes, int n_in,
                              void* d_out, int out_size, void* d_ws, size_t ws_size,
                              hipStream_t stream) {
  const float* pot = (const float*)d_in[0];
  const int* tags = (const int*)d_in[1];
  const float* trans = (const float*)d_in[2];
  float* out = (float*)d_out;
  unsigned short* wsv = (unsigned short*)d_ws;            // 512 x 2 x 128 bf16
  float4* wsm = (float4*)((char*)d_ws + (size_t)512 * 2 * KK * 2);
  crf_half_kernel<<<2 * BB / 2, 256, 0, stream>>>(pot, tags, trans, wsv, wsm);
  crf_combine_kernel<<<BB / 4, 256, 0, stream>>>(wsv, wsm, out);
}